// Round 1
// baseline (6258.169 us; speedup 1.0000x reference)
//
#include <hip/hip_runtime.h>
#include <math.h>

#define NPTS 256
#define NB 8
#define CPL 4  // columns per lane (64 lanes * 4 = 256)

// fp64 Euclidean distance with fma-contraction off so it is bit-identical to
// numpy's ((d0*d0 + d1*d1) + d2*d2) followed by IEEE sqrt.
__device__ __forceinline__ double dist3d(double ax, double ay, double az,
                                         double bx, double by, double bz) {
#pragma clang fp contract(off)
  double d0 = ax - bx;
  double d1 = ay - by;
  double d2 = az - bz;
  double s = d0 * d0;
  s = s + d1 * d1;
  s = s + d2 * d2;
  return sqrt(s);
}

// One block (one 64-lane wave) per batch sample. Shortest-augmenting-path
// linear sum assignment, bit-exact port of the reference _lsa_square.
__global__ __launch_bounds__(64) void emd_lsa_kernel(
    const float* __restrict__ pred, const float* __restrict__ label,
    double* __restrict__ partial) {
  __shared__ double xs0[NPTS], xs1[NPTS], xs2[NPTS];
  __shared__ double ys0[NPTS], ys1[NPTS], ys2[NPTS];
  __shared__ double u_l[NPTS];      // row duals
  __shared__ double short_l[NPTS];  // shortest[] published for scanned cols
  __shared__ int path_l[NPTS];      // path[] published for scanned cols
  __shared__ int c4r_l[NPTS];       // col4row
  __shared__ int r4c_l[NPTS];       // row4col
  __shared__ int sr_l[NPTS];        // scanned-rows flags

  const int lane = threadIdx.x;
  const int b = blockIdx.x;
  const float* xg = pred + (size_t)b * NPTS * 3;
  const float* yg = label + (size_t)b * NPTS * 3;

  // Per-lane column state in registers.
  double ycol0[CPL], ycol1[CPL], ycol2[CPL];
  double v_reg[CPL];  // column duals

  for (int c = 0; c < CPL; ++c) {
    int j = lane * CPL + c;
    xs0[j] = (double)xg[j * 3 + 0];
    xs1[j] = (double)xg[j * 3 + 1];
    xs2[j] = (double)xg[j * 3 + 2];
    double t0 = (double)yg[j * 3 + 0];
    double t1 = (double)yg[j * 3 + 1];
    double t2 = (double)yg[j * 3 + 2];
    ys0[j] = t0; ys1[j] = t1; ys2[j] = t2;
    ycol0[c] = t0; ycol1[c] = t1; ycol2[c] = t2;
    u_l[j] = 0.0;
    c4r_l[j] = -1;
    r4c_l[j] = -1;
    v_reg[c] = 0.0;
  }
  __syncthreads();

  const double INF = __builtin_inf();

  for (int cur_row = 0; cur_row < NPTS; ++cur_row) {
    double shortest[CPL];
    int scanned[CPL];
    int path_r[CPL];
    for (int c = 0; c < CPL; ++c) {
      shortest[c] = INF;
      scanned[c] = 0;
      path_r[c] = -1;
      sr_l[lane * CPL + c] = 0;
    }
    __syncthreads();

    double min_val = 0.0;
    int i = cur_row;  // uniform across the wave
    int sink = -1;

    // Dijkstra over columns; barrier-free inner loop (cross-lane comm is
    // shuffle-only; LDS touched here is read-only or read-after-later-sync).
    while (true) {
      sr_l[i] = 1;  // same addr+value from all lanes
      double xi0 = xs0[i], xi1 = xs1[i], xi2 = xs2[i];
      double ui = u_l[i];
      double best = INF;
      int bidx = NPTS;
      for (int c = 0; c < CPL; ++c) {
        if (!scanned[c]) {
          double cst = dist3d(xi0, xi1, xi2, ycol0[c], ycol1[c], ycol2[c]);
          double r = ((min_val + cst) - ui) - v_reg[c];
          if (r < shortest[c]) { shortest[c] = r; path_r[c] = i; }
          if (shortest[c] < best) {  // strict < => lowest col index on ties
            best = shortest[c];
            bidx = lane * CPL + c;
          }
        }
      }
      // Wave-wide lexicographic (value, index) argmin butterfly.
      double val = best;
      int idx = bidx;
      for (int m = 1; m < 64; m <<= 1) {
        double ov = __shfl_xor(val, m);
        int oi = __shfl_xor(idx, m);
        if (ov < val || (ov == val && oi < idx)) { val = ov; idx = oi; }
      }
      min_val = val;
      int jstar = idx;
      if ((jstar >> 2) == lane) {  // owner publishes scanned-col state
        int c = jstar & (CPL - 1);
        scanned[c] = 1;
        short_l[jstar] = shortest[c];
        path_l[jstar] = path_r[c];
      }
      int nr = r4c_l[jstar];  // read-only during this Dijkstra
      if (nr < 0) { sink = jstar; break; }
      i = nr;
    }
    __syncthreads();  // publish short_l / path_l / sr_l writes

    // Dual update (before augmentation, matching the reference).
    for (int c = 0; c < CPL; ++c) {
      int row = lane * CPL + c;
      if (sr_l[row]) {
        if (row == cur_row) u_l[row] += min_val;
        else u_l[row] += min_val - short_l[c4r_l[row]];
      }
      if (scanned[c]) v_reg[c] -= min_val - shortest[c];
    }
    __syncthreads();  // dual reads of c4r_l done before augmentation writes

    if (lane == 0) {  // augment along alternating path (short, sequential)
      int jj = sink;
      while (true) {
        int ii = path_l[jj];
        r4c_l[jj] = ii;
        int tmp = c4r_l[ii];
        c4r_l[ii] = jj;
        jj = tmp;
        if (ii == cur_row) break;
      }
    }
    __syncthreads();
  }

  // Partial loss: sum of matched distances for this batch.
  double s = 0.0;
  for (int c = 0; c < CPL; ++c) {
    int row = lane * CPL + c;
    int j = c4r_l[row];
    s += dist3d(xs0[row], xs1[row], xs2[row], ys0[j], ys1[j], ys2[j]);
  }
  for (int m = 1; m < 64; m <<= 1) s += __shfl_xor(s, m);
  if (lane == 0) partial[b] = s;
}

__global__ void emd_finalize_kernel(const double* __restrict__ partial,
                                    float* __restrict__ out) {
  if (threadIdx.x == 0 && blockIdx.x == 0) {
    double s = 0.0;
    for (int b = 0; b < NB; ++b) s += partial[b];
    out[0] = (float)(s / (double)(NB * NPTS));
  }
}

extern "C" void kernel_launch(void* const* d_in, const int* in_sizes, int n_in,
                              void* d_out, int out_size, void* d_ws, size_t ws_size,
                              hipStream_t stream) {
  const float* pred = (const float*)d_in[0];
  const float* label = (const float*)d_in[1];
  double* partial = (double*)d_ws;  // 8 doubles
  emd_lsa_kernel<<<NB, 64, 0, stream>>>(pred, label, partial);
  emd_finalize_kernel<<<1, 64, 0, stream>>>(partial, (float*)d_out);
}

// Round 2
// 1320.734 us; speedup vs baseline: 4.7384x; 4.7384x over previous
//
#include <hip/hip_runtime.h>
#include <math.h>

#define NPTS 256
#define NB 8
#define CPL 4  // columns (and rows) per lane: 64 lanes * 4 = 256

#if __has_builtin(__builtin_amdgcn_sqrtf)
#define FSQRT __builtin_amdgcn_sqrtf
#else
#define FSQRT sqrtf
#endif

// Exact fp64 distance (contract off) for the final loss value: bit-matches
// numpy's ((d0*d0 + d1*d1) + d2*d2) then IEEE sqrt on f64-cast f32 inputs.
__device__ __forceinline__ double dist3d(double ax, double ay, double az,
                                         double bx, double by, double bz) {
#pragma clang fp contract(off)
  double d0 = ax - bx;
  double d1 = ay - by;
  double d2 = az - bz;
  double s = d0 * d0;
  s = s + d1 * d1;
  s = s + d2 * d2;
  return sqrt(s);
}

__device__ __forceinline__ float distf(float ax, float ay, float az,
                                       float bx, float by, float bz) {
  float d0 = ax - bx, d1 = ay - by, d2 = az - bz;
  return FSQRT(d0 * d0 + d1 * d1 + d2 * d2);
}

// Wave64 min-reduce of a u32 via DPP (row_shr 1/2/4/8 + row_bcast 15/31),
// result broadcast via readlane(63). Pure VALU/SALU — no LDS traffic.
__device__ __forceinline__ unsigned wave_min_u32(unsigned x) {
  int v = (int)x;
  v = min(v ^ 0, v);  // keep as int ops; unsigned min via builtin below
  unsigned r = x;
  r = min(r, (unsigned)__builtin_amdgcn_update_dpp((int)r, (int)r, 0x111, 0xF, 0xF, false));  // row_shr:1
  r = min(r, (unsigned)__builtin_amdgcn_update_dpp((int)r, (int)r, 0x112, 0xF, 0xF, false));  // row_shr:2
  r = min(r, (unsigned)__builtin_amdgcn_update_dpp((int)r, (int)r, 0x114, 0xF, 0xF, false));  // row_shr:4
  r = min(r, (unsigned)__builtin_amdgcn_update_dpp((int)r, (int)r, 0x118, 0xF, 0xF, false));  // row_shr:8
  r = min(r, (unsigned)__builtin_amdgcn_update_dpp((int)r, (int)r, 0x142, 0xF, 0xF, false));  // row_bcast:15
  r = min(r, (unsigned)__builtin_amdgcn_update_dpp((int)r, (int)r, 0x143, 0xF, 0xF, false));  // row_bcast:31
  return (unsigned)__builtin_amdgcn_readlane((int)r, 63);
}

// One block = one 64-lane wave per batch sample.
// JV-style LSA: column-reduction duals + greedy partial assignment, then
// shortest-augmenting-path (Dijkstra) for the remaining free rows.
// fp32 solver; optimal value is permutation-level identical (to fp32 noise).
__global__ __launch_bounds__(64) void emd_lsa_kernel(
    const float* __restrict__ pred, const float* __restrict__ label,
    double* __restrict__ partial) {
  __shared__ float4 rowd[NPTS];     // {x0, x1, x2, u}
  __shared__ float ys0[NPTS], ys1[NPTS], ys2[NPTS];
  __shared__ float short_l[NPTS];   // shortest[] published for scanned cols
  __shared__ int path_l[NPTS];      // path[] published for scanned cols
  __shared__ int c4r_l[NPTS];       // col4row
  __shared__ int r4c_l[NPTS];       // row4col
  __shared__ int sr_l[NPTS];        // scanned-row flags
  __shared__ int bcfr[NPTS];        // greedy: best (lowest) col per row

  const int lane = threadIdx.x;
  const int b = blockIdx.x;
  const float* xg = pred + (size_t)b * NPTS * 3;
  const float* yg = label + (size_t)b * NPTS * 3;

  float yc0[CPL], yc1[CPL], yc2[CPL];  // owned columns' coords
  float v_reg[CPL];                    // column duals
  int r4c_reg[CPL];                    // mirror of r4c_l for owned cols

#pragma unroll
  for (int c = 0; c < CPL; ++c) {
    int j = lane * CPL + c;
    rowd[j] = make_float4(xg[j * 3 + 0], xg[j * 3 + 1], xg[j * 3 + 2], 0.0f);
    float t0 = yg[j * 3 + 0], t1 = yg[j * 3 + 1], t2 = yg[j * 3 + 2];
    ys0[j] = t0; ys1[j] = t1; ys2[j] = t2;
    yc0[c] = t0; yc1[c] = t1; yc2[c] = t2;
    c4r_l[j] = -1;
    r4c_l[j] = -1;
    bcfr[j] = 0x7FFFFFFF;
  }
  __syncthreads();

  // ---- Column reduction: v[j] = min_i cost[i][j], with argmin row. ----
  float cmin[CPL];
  int imin[CPL];
#pragma unroll
  for (int c = 0; c < CPL; ++c) { cmin[c] = 3.4e38f; imin[c] = -1; }
  for (int i = 0; i < NPTS; ++i) {
    float4 rd = rowd[i];  // broadcast read
#pragma unroll
    for (int c = 0; c < CPL; ++c) {
      float d = distf(rd.x, rd.y, rd.z, yc0[c], yc1[c], yc2[c]);
      bool upd = d < cmin[c];
      cmin[c] = upd ? d : cmin[c];
      imin[c] = upd ? i : imin[c];
    }
  }
#pragma unroll
  for (int c = 0; c < CPL; ++c) {
    v_reg[c] = cmin[c];
    atomicMin(&bcfr[imin[c]], lane * CPL + c);  // LDS atomic, deterministic
  }
  __syncthreads();
  // Greedy: col j gets its argmin row iff j is the lowest col claiming it.
#pragma unroll
  for (int c = 0; c < CPL; ++c) {
    int j = lane * CPL + c;
    if (bcfr[imin[c]] == j) {
      r4c_l[j] = imin[c];
      c4r_l[imin[c]] = j;
    }
  }
  __syncthreads();
#pragma unroll
  for (int c = 0; c < CPL; ++c) r4c_reg[c] = r4c_l[lane * CPL + c];
  __syncthreads();

  const float INF = 3.4e38f;

  // ---- Shortest augmenting path for each remaining free row. ----
  for (int cur_row = 0; cur_row < NPTS; ++cur_row) {
    if (c4r_l[cur_row] != -1) continue;  // uniform

    float shortest[CPL];
    int path_r[CPL];
    int scn[CPL];
#pragma unroll
    for (int c = 0; c < CPL; ++c) {
      shortest[c] = INF;
      path_r[c] = -1;
      scn[c] = 0;
      sr_l[lane * CPL + c] = 0;
    }
    __syncthreads();

    float min_val = 0.0f;
    int i = cur_row;  // uniform
    int sink = -1;

    while (true) {
      sr_l[i] = 1;
      float4 rd = rowd[i];  // {x,y,z,u[i]} broadcast ds_read_b128
      float base = min_val - rd.w;
      unsigned lkey = 0xFFFFFFFFu;
#pragma unroll
      for (int c = 0; c < CPL; ++c) {
        float cst = distf(rd.x, rd.y, rd.z, yc0[c], yc1[c], yc2[c]);
        float r = (base + cst) - v_reg[c];
        bool upd = (r < shortest[c]) && !scn[c];
        shortest[c] = upd ? r : shortest[c];
        path_r[c] = upd ? i : path_r[c];
        float snn = fmaxf(shortest[c], 0.0f);  // keep u32 order == f32 order
        unsigned k = (__float_as_uint(snn) & 0xFFFFFF00u) | (unsigned)(lane * CPL + c);
        k = scn[c] ? 0xFFFFFFFFu : k;
        lkey = min(lkey, k);
      }
      unsigned best = wave_min_u32(lkey);
      int jstar = (int)(best & 0xFFu);
      int csel = jstar & (CPL - 1);
      int owner = jstar >> 2;

      // Owner publishes scanned-col state (off critical path stores).
      if (owner == lane) {
        scn[csel] = 1;
        short_l[jstar] = shortest[csel];
        path_l[jstar] = path_r[csel];
      }
      // Exact min_val and next row from owner-lane registers (2 shuffles).
      float slo = (csel & 1) ? shortest[1] : shortest[0];
      float shi = (csel & 1) ? shortest[3] : shortest[2];
      float ssel = (csel & 2) ? shi : slo;
      int rlo = (csel & 1) ? r4c_reg[1] : r4c_reg[0];
      int rhi = (csel & 1) ? r4c_reg[3] : r4c_reg[2];
      int rsel = (csel & 2) ? rhi : rlo;
      min_val = __shfl(ssel, owner);
      int nr = __shfl(rsel, owner);
      if (nr < 0) { sink = jstar; break; }
      i = nr;
    }
    __syncthreads();  // publish short_l / path_l / sr_l

    // Dual update (rows via LDS flags, cols via register state).
#pragma unroll
    for (int c = 0; c < CPL; ++c) {
      int row = lane * CPL + c;
      if (sr_l[row]) {
        float du = (row == cur_row) ? min_val : (min_val - short_l[c4r_l[row]]);
        rowd[row].w += du;
      }
      if (scn[c]) v_reg[c] -= min_val - shortest[c];
    }
    __syncthreads();

    if (lane == 0) {  // augment along the alternating path
      int jj = sink;
      while (true) {
        int ii = path_l[jj];
        r4c_l[jj] = ii;
        int tmp = c4r_l[ii];
        c4r_l[ii] = jj;
        jj = tmp;
        if (ii == cur_row) break;
      }
    }
    __syncthreads();
#pragma unroll
    for (int c = 0; c < CPL; ++c) r4c_reg[c] = r4c_l[lane * CPL + c];
    __syncthreads();
  }

  // ---- Final loss: exact fp64 matched distances. ----
  double s = 0.0;
#pragma unroll
  for (int c = 0; c < CPL; ++c) {
    int row = lane * CPL + c;
    int j = c4r_l[row];
    float4 rd = rowd[row];
    s += dist3d((double)rd.x, (double)rd.y, (double)rd.z,
                (double)ys0[j], (double)ys1[j], (double)ys2[j]);
  }
  for (int m = 1; m < 64; m <<= 1) s += __shfl_xor(s, m);
  if (lane == 0) partial[b] = s;
}

__global__ void emd_finalize_kernel(const double* __restrict__ partial,
                                    float* __restrict__ out) {
  if (threadIdx.x == 0 && blockIdx.x == 0) {
    double s = 0.0;
    for (int b = 0; b < NB; ++b) s += partial[b];
    out[0] = (float)(s / (double)(NB * NPTS));
  }
}

extern "C" void kernel_launch(void* const* d_in, const int* in_sizes, int n_in,
                              void* d_out, int out_size, void* d_ws, size_t ws_size,
                              hipStream_t stream) {
  const float* pred = (const float*)d_in[0];
  const float* label = (const float*)d_in[1];
  double* partial = (double*)d_ws;  // 8 doubles
  emd_lsa_kernel<<<NB, 64, 0, stream>>>(pred, label, partial);
  emd_finalize_kernel<<<1, 64, 0, stream>>>(partial, (float*)d_out);
}